// Round 3
// baseline (1225.397 us; speedup 1.0000x reference)
//
#include <hip/hip_runtime.h>

#define LNUM 4
#define DMODEL 1024
#define NHEAD 16
#define FDIM 4096
#define BATCH 4
#define SEQ 1024
#define HDIM 64
#define KBAND 8
#define MROWS (BATCH * SEQ)

typedef __attribute__((ext_vector_type(8))) __bf16 bf16x8;
typedef __attribute__((ext_vector_type(4))) float f32x4;

__device__ __forceinline__ unsigned short f2bf(float f) {
  unsigned int u = __builtin_bit_cast(unsigned int, f);
  u = u + 0x7fffu + ((u >> 16) & 1u);
  return (unsigned short)(u >> 16);
}
__device__ __forceinline__ float bf2f(unsigned short h) {
  unsigned int u = ((unsigned int)h) << 16;
  return __builtin_bit_cast(float, u);
}

#define GLOAD16(gp, lp)                                                        \
  __builtin_amdgcn_global_load_lds(                                            \
      (const __attribute__((address_space(1))) void*)(gp),                     \
      (__attribute__((address_space(3))) void*)(lp), 16, 0, 0)

// ---------------- fp32 -> bf16 conversion (vectorized, 4/thread) -----------
__global__ __launch_bounds__(256) void cvt_bf16(const float* __restrict__ in,
                                                unsigned short* __restrict__ out,
                                                long n) {
  long i = ((long)blockIdx.x * 256 + threadIdx.x) * 4;
  if (i + 3 < n) {
    float4 v = *reinterpret_cast<const float4*>(in + i);
    ushort4 o;
    o.x = f2bf(v.x);
    o.y = f2bf(v.y);
    o.z = f2bf(v.z);
    o.w = f2bf(v.w);
    *reinterpret_cast<ushort4*>(out + i) = o;
  }
}

// ---------------- bf16 GEMM, C = A * W^T + bias --------------------------
// A: [M,K] bf16 row-major.  W: [N,K] bf16 row-major (== B^T).
// 128x128 tile, BK=64, double-buffered LDS, 2-phase pipeline (T3-minimum):
//   STAGE(next) -> COMPUTE(cur) -> barrier (one per iter; implicit vmcnt drain)
// 256 threads = 4 waves (2x2), 4x4 16x16x32 MFMA per wave per k-step.
// blockIdx.z = K-split index (K range [z*Ks, (z+1)*Ks)); Ks % 64 == 0.
// EPI: 0 = bf16 out (+bias), 1 = bf16 out (+bias, exact gelu),
//      2 = f32 partial out (bias only on z==0), per-z slab of M*N floats.
template <int EPI>
__global__ __launch_bounds__(256) void gemm_bt(const unsigned short* __restrict__ A,
                                               const unsigned short* __restrict__ W,
                                               const float* __restrict__ bias,
                                               void* __restrict__ Cout,
                                               int Ndim, int Kdim, int Ks) {
  __shared__ unsigned short Asl[2][128 * 64];
  __shared__ unsigned short Bsl[2][128 * 64];
  const int tid = threadIdx.x;
  const int wave = tid >> 6;
  const int lane = tid & 63;

  // XCD-aware swizzle, n-column-band chunks (requires gridDim.x % 8 == 0):
  // XCD x owns n-cols [x*colw, (x+1)*colw); within the band, n-fastest order
  // keeps both the B slab (colw * 256KB) and the active A rows L2-resident.
  const int gx = gridDim.x, gy = gridDim.y;
  const int colw = gx >> 3;
  const int lin = blockIdx.x + blockIdx.y * gx;
  const int xcd = lin & 7;
  const int idx = lin >> 3;
  const int bn0 = (xcd * colw + idx % colw) * 128;
  const int bm0 = (idx / colw) * 128;

  const int kz0 = blockIdx.z * Ks;

  // staging geometry: tile [128][64] bf16 = 16 KB = 4 instrs x 256 thr x 16 B
  const int r0 = tid >> 3;        // row 0..31 (instr i adds i*32)
  const int c0 = (tid & 7) * 8;   // k-col 0..56
  const unsigned short* gA = A + (size_t)(bm0 + r0) * Kdim + kz0 + c0;
  const unsigned short* gB = W + (size_t)(bn0 + r0) * Kdim + kz0 + c0;
  const size_t rstep = (size_t)32 * Kdim;

  f32x4 acc[4][4] = {};

  const int wr = (wave >> 1) * 64;  // wave row origin in tile
  const int wc = (wave & 1) * 64;   // wave col origin in tile
  const int frow = lane & 15;
  const int kof = (lane >> 4) * 8;
  const int wb = wave * 512;        // per-wave element base within 2K chunk

#define STAGE(buf)                                                             \
  do {                                                                         \
    GLOAD16(gA, &Asl[buf][0 * 2048 + wb]);                                     \
    GLOAD16(gA + rstep, &Asl[buf][1 * 2048 + wb]);                             \
    GLOAD16(gA + 2 * rstep, &Asl[buf][2 * 2048 + wb]);                         \
    GLOAD16(gA + 3 * rstep, &Asl[buf][3 * 2048 + wb]);                         \
    GLOAD16(gB, &Bsl[buf][0 * 2048 + wb]);                                     \
    GLOAD16(gB + rstep, &Bsl[buf][1 * 2048 + wb]);                             \
    GLOAD16(gB + 2 * rstep, &Bsl[buf][2 * 2048 + wb]);                         \
    GLOAD16(gB + 3 * rstep, &Bsl[buf][3 * 2048 + wb]);                         \
    gA += 64;                                                                  \
    gB += 64;                                                                  \
  } while (0)

#define COMPUTE(buf)                                                           \
  do {                                                                         \
    _Pragma("unroll")                                                          \
    for (int ks = 0; ks < 2; ++ks) {                                           \
      bf16x8 af[4], bfr[4];                                                    \
      _Pragma("unroll")                                                        \
      for (int i = 0; i < 4; ++i)                                              \
        af[i] = *reinterpret_cast<const bf16x8*>(                              \
            &Asl[buf][(wr + i * 16 + frow) * 64 + ks * 32 + kof]);             \
      _Pragma("unroll")                                                        \
      for (int j = 0; j < 4; ++j)                                              \
        bfr[j] = *reinterpret_cast<const bf16x8*>(                             \
            &Bsl[buf][(wc + j * 16 + frow) * 64 + ks * 32 + kof]);             \
      _Pragma("unroll")                                                        \
      for (int i = 0; i < 4; ++i)                                              \
        _Pragma("unroll")                                                      \
        for (int j = 0; j < 4; ++j)                                            \
          acc[i][j] = __builtin_amdgcn_mfma_f32_16x16x32_bf16(                 \
              af[i], bfr[j], acc[i][j], 0, 0, 0);                              \
    }                                                                          \
  } while (0)

  const int nt = Ks >> 6;
  STAGE(0);
  __syncthreads();  // implicit vmcnt(0) drain: buf0 staged
  int cur = 0;
  for (int t = 0; t < nt - 1; ++t) {
    STAGE(cur ^ 1);   // issue next tile's loads first (overlap with compute)
    COMPUTE(cur);
    __syncthreads();  // drains stage loads; joins LDS reads before overwrite
    cur ^= 1;
  }
  COMPUTE(cur);

#undef STAGE
#undef COMPUTE

  // C/D layout (verified m89/m91): col = lane&15, row = (lane>>4)*4 + reg
  const int rr = (lane >> 4) * 4;
  const int cc = lane & 15;
  const bool addb = (EPI != 2) || (blockIdx.z == 0);
  float* outF = reinterpret_cast<float*>(Cout) +
                (size_t)blockIdx.z * ((size_t)gy * 128) * Ndim;
#pragma unroll
  for (int j = 0; j < 4; ++j) {
    const int n = bn0 + wc + j * 16 + cc;
    const float bv = addb ? bias[n] : 0.0f;
#pragma unroll
    for (int i = 0; i < 4; ++i) {
#pragma unroll
      for (int r = 0; r < 4; ++r) {
        const int m = bm0 + wr + i * 16 + rr + r;
        float v = acc[i][j][r] + bv;
        if (EPI == 1) v = 0.5f * v * (1.0f + erff(v * 0.70710678118654752f));
        if (EPI == 2) {
          outF[(size_t)m * Ndim + n] = v;
        } else {
          reinterpret_cast<unsigned short*>(Cout)[(size_t)m * Ndim + n] = f2bf(v);
        }
      }
    }
  }
}

// ---------------- banded attention: one wave per (b,h,q), lane = d ----------
__global__ __launch_bounds__(256) void attn_band(const unsigned short* __restrict__ qkv,
                                                 unsigned short* __restrict__ outp) {
  const int gw = blockIdx.x * 4 + (threadIdx.x >> 6);
  const int lane = threadIdx.x & 63;
  const int q = gw & (SEQ - 1);
  const int bh = gw >> 10;  // SEQ = 1024
  const int h = bh & (NHEAD - 1);
  const int b = bh >> 4;
  const size_t row0 = (size_t)(b * SEQ + q);
  const size_t stride = 3 * DMODEL;
  const float qv = bf2f(qkv[row0 * stride + h * HDIM + lane]);

  float sc[KBAND];
  float mx = -1e30f;
#pragma unroll
  for (int jj = 0; jj < KBAND; ++jj) {
    const int j = q + jj;
    const int jc = (j < SEQ) ? j : (SEQ - 1);
    float kv = bf2f(qkv[(size_t)(b * SEQ + jc) * stride + DMODEL + h * HDIM + lane]);
    float p = qv * kv;
#pragma unroll
    for (int m = 32; m; m >>= 1) p += __shfl_xor(p, m);
    p *= 0.125f;  // 1/sqrt(64)
    p = (j < SEQ) ? p : -1e30f;
    sc[jj] = p;
    mx = fmaxf(mx, p);
  }
  float denom = 0.f;
  float ov = 0.f;
#pragma unroll
  for (int jj = 0; jj < KBAND; ++jj) {
    const int j = q + jj;
    const int jc = (j < SEQ) ? j : (SEQ - 1);
    float p = __expf(sc[jj] - mx);
    p = (j < SEQ) ? p : 0.f;
    denom += p;
    ov += p * bf2f(qkv[(size_t)(b * SEQ + jc) * stride + 2 * DMODEL + h * HDIM + lane]);
  }
  ov /= denom;
  outp[row0 * DMODEL + h * HDIM + lane] = f2bf(ov);
}

// ---------------- fused residual add + 2-way split-K reduce + LayerNorm ----
// y = LN(resid + d0 + d1); writes fp32 (next residual / final out) + bf16
__global__ __launch_bounds__(256) void add_ln(const float* __restrict__ resid,
                                              const float* __restrict__ d0,
                                              const float* __restrict__ d1,
                                              const float* __restrict__ gw,
                                              const float* __restrict__ gb,
                                              float* __restrict__ xf,
                                              unsigned short* __restrict__ xb) {
  const int row = blockIdx.x;
  const int tid = threadIdx.x;
  const float* rp = resid + (size_t)row * DMODEL;
  const float* p0 = d0 + (size_t)row * DMODEL;
  const float* p1 = d1 + (size_t)row * DMODEL;
  float v[4];
  float s = 0.f, s2 = 0.f;
#pragma unroll
  for (int i = 0; i < 4; ++i) {
    const int idx = tid + i * 256;
    v[i] = rp[idx] + p0[idx] + p1[idx];
    s += v[i];
    s2 += v[i] * v[i];
  }
#pragma unroll
  for (int m = 32; m; m >>= 1) {
    s += __shfl_xor(s, m);
    s2 += __shfl_xor(s2, m);
  }
  __shared__ float wsm[8];
  const int wave = tid >> 6, lane = tid & 63;
  if (lane == 0) {
    wsm[wave] = s;
    wsm[4 + wave] = s2;
  }
  __syncthreads();
  s = wsm[0] + wsm[1] + wsm[2] + wsm[3];
  s2 = wsm[4] + wsm[5] + wsm[6] + wsm[7];
  const float mean = s * (1.f / DMODEL);
  const float var = s2 * (1.f / DMODEL) - mean * mean;
  const float rstd = rsqrtf(var + 1e-5f);
#pragma unroll
  for (int i = 0; i < 4; ++i) {
    const int idx = tid + i * 256;
    const float y = (v[i] - mean) * rstd * gw[idx] + gb[idx];
    xf[(size_t)row * DMODEL + idx] = y;
    xb[(size_t)row * DMODEL + idx] = f2bf(y);
  }
}

extern "C" void kernel_launch(void* const* d_in, const int* in_sizes, int n_in,
                              void* d_out, int out_size, void* d_ws, size_t ws_size,
                              hipStream_t stream) {
  const float* src  = (const float*)d_in[0];
  const float* Wqkv = (const float*)d_in[1];
  const float* bqkv = (const float*)d_in[2];
  const float* Wo   = (const float*)d_in[3];
  const float* bo   = (const float*)d_in[4];
  const float* W1   = (const float*)d_in[5];
  const float* b1   = (const float*)d_in[6];
  const float* W2   = (const float*)d_in[7];
  const float* b2   = (const float*)d_in[8];
  const float* ln1w = (const float*)d_in[9];
  const float* ln1b = (const float*)d_in[10];
  const float* ln2w = (const float*)d_in[11];
  const float* ln2b = (const float*)d_in[12];
  float* out = (float*)d_out;

  // workspace carve-up (needs 192,937,984 B of the 209,715,200 provided)
  char* p = (char*)d_ws;
  unsigned short* wqkv_b = (unsigned short*)p; p += (size_t)LNUM * 3072 * 1024 * 2;
  unsigned short* wo_b   = (unsigned short*)p; p += (size_t)LNUM * 1024 * 1024 * 2;
  unsigned short* w1_b   = (unsigned short*)p; p += (size_t)LNUM * 4096 * 1024 * 2;
  unsigned short* w2_b   = (unsigned short*)p; p += (size_t)LNUM * 1024 * 4096 * 2;
  float*          xf     = (float*)p;          p += (size_t)MROWS * DMODEL * 4;
  unsigned short* xb     = (unsigned short*)p; p += (size_t)MROWS * DMODEL * 2;
  // scratch region R, time-multiplexed:
  //   [R +0      .. +25.2MB) qkvb   (bf16, live QKV gemm -> attn)
  //   [R +25.2MB .. +33.6MB) aob    (bf16, live attn -> Wo gemm)
  //   [R +0      .. +33.6MB) hb     (bf16, live W1 gemm -> W2 gemm; aliases qkvb+aob)
  //   [R +33.6MB .. +67.2MB) p0,p1  (f32 split-K partials, live gemm -> add_ln)
  char* R = p;
  unsigned short* qkvb = (unsigned short*)R;
  unsigned short* aob  = (unsigned short*)(R + (size_t)MROWS * 3 * DMODEL * 2);
  unsigned short* hb   = (unsigned short*)R;  // aliases qkvb+aob (33.6 MB)
  float* part          = (float*)(R + (size_t)MROWS * 4096 * 2);
  p = R + (size_t)MROWS * 4096 * 2 + (size_t)2 * MROWS * DMODEL * 4;
  if (ws_size < (size_t)(p - (char*)d_ws)) return;  // insufficient scratch

  // fp32 -> bf16 weights + initial activation
  cvt_bf16<<<(long)LNUM * 3072 * 1024 / 1024, 256, 0, stream>>>(Wqkv, wqkv_b, (long)LNUM * 3072 * 1024);
  cvt_bf16<<<(long)LNUM * 1024 * 1024 / 1024, 256, 0, stream>>>(Wo, wo_b, (long)LNUM * 1024 * 1024);
  cvt_bf16<<<(long)LNUM * 4096 * 1024 / 1024, 256, 0, stream>>>(W1, w1_b, (long)LNUM * 4096 * 1024);
  cvt_bf16<<<(long)LNUM * 1024 * 4096 / 1024, 256, 0, stream>>>(W2, w2_b, (long)LNUM * 1024 * 4096);
  cvt_bf16<<<(long)MROWS * DMODEL / 1024, 256, 0, stream>>>(src, xb, (long)MROWS * DMODEL);

  for (int l = 0; l < LNUM; ++l) {
    // QKV projection: [4096,1024] x [3072,1024]^T -> bf16 [4096,3072]
    gemm_bt<0><<<dim3(3072 / 128, MROWS / 128, 1), 256, 0, stream>>>(
        xb, wqkv_b + (size_t)l * 3072 * 1024, bqkv + l * 3072, qkvb, 3072, 1024, 1024);
    // banded attention -> bf16 [4096,1024]
    attn_band<<<(BATCH * NHEAD * SEQ) / 4, 256, 0, stream>>>(qkvb, aob);
    // output projection, split-K=2 (Ks=512) -> f32 partials p0,p1
    gemm_bt<2><<<dim3(1024 / 128, MROWS / 128, 2), 256, 0, stream>>>(
        aob, wo_b + (size_t)l * 1024 * 1024, bo + l * 1024, part, 1024, 1024, 512);
    // x = LN(x + p0 + p1)
    add_ln<<<MROWS, 256, 0, stream>>>(l == 0 ? src : xf, part, part + (size_t)MROWS * DMODEL,
                                      ln1w + l * DMODEL, ln1b + l * DMODEL, xf, xb);
    // FFN up + exact gelu -> bf16 [4096,4096]
    gemm_bt<1><<<dim3(FDIM / 128, MROWS / 128, 1), 256, 0, stream>>>(
        xb, w1_b + (size_t)l * 4096 * 1024, b1 + l * FDIM, hb, FDIM, 1024, 1024);
    // FFN down, split-K=2 (K=4096 -> 2x2048) -> f32 partials
    gemm_bt<2><<<dim3(1024 / 128, MROWS / 128, 2), 256, 0, stream>>>(
        hb, w2_b + (size_t)l * 1024 * 4096, b2 + l * 1024, part, 1024, 4096, 2048);
    // x = LN(x + p0 + p1); last layer writes d_out
    float* dst = (l == LNUM - 1) ? out : xf;
    add_ln<<<MROWS, 256, 0, stream>>>(xf, part, part + (size_t)MROWS * DMODEL,
                                      ln2w + l * DMODEL, ln2b + l * DMODEL, dst, xb);
  }
}

// Round 4
// 1110.687 us; speedup vs baseline: 1.1033x; 1.1033x over previous
//
#include <hip/hip_runtime.h>

#define LNUM 4
#define DMODEL 1024
#define NHEAD 16
#define FDIM 4096
#define BATCH 4
#define SEQ 1024
#define HDIM 64
#define KBAND 8
#define MROWS (BATCH * SEQ)

typedef __attribute__((ext_vector_type(8))) __bf16 bf16x8;
typedef __attribute__((ext_vector_type(4))) float f32x4;

__device__ __forceinline__ unsigned short f2bf(float f) {
  unsigned int u = __builtin_bit_cast(unsigned int, f);
  u = u + 0x7fffu + ((u >> 16) & 1u);
  return (unsigned short)(u >> 16);
}
__device__ __forceinline__ float bf2f(unsigned short h) {
  unsigned int u = ((unsigned int)h) << 16;
  return __builtin_bit_cast(float, u);
}

#define GLOAD16(gp, lp)                                                        \
  __builtin_amdgcn_global_load_lds(                                            \
      (const __attribute__((address_space(1))) void*)(gp),                     \
      (__attribute__((address_space(3))) void*)(lp), 16, 0, 0)

// ---------------- fp32 -> bf16 conversion -----------------------------------
__global__ __launch_bounds__(256) void cvt_bf16(const float* __restrict__ in,
                                                unsigned short* __restrict__ out,
                                                long n) {
  long i = ((long)blockIdx.x * 256 + threadIdx.x) * 4;
  if (i + 3 < n) {
    float4 v = *reinterpret_cast<const float4*>(in + i);
    ushort4 o;
    o.x = f2bf(v.x);
    o.y = f2bf(v.y);
    o.z = f2bf(v.z);
    o.w = f2bf(v.w);
    *reinterpret_cast<ushort4*>(out + i) = o;
  }
}

// ---------------- 256x256 8-phase bf16 GEMM, C = A * W^T + bias -------------
// A: [M,K] bf16 rm. W: [N,K] bf16 rm. 512 thr = 8 waves (2m x 4n).
// BK=64, LDS 128KB double-buffer, per-wave out 128x64 (acc 2x2x4x2 f32x4).
// 8 phases / iter (2 K-tiles). Counted vmcnt(6) at phases 3/7 only (T4);
// setprio around MFMA (T5). blockIdx.z = K-split (range [z*Ks,(z+1)*Ks)).
// EPI: 0 = bf16 (+bias), 1 = bf16 (+bias, exact gelu),
//      2 = bf16 PARTIAL slab per z (bias only z==0).
#define BAR_MID()                                                              \
  __builtin_amdgcn_s_barrier();                                                \
  asm volatile("s_waitcnt lgkmcnt(0)" ::: "memory");                           \
  __builtin_amdgcn_sched_barrier(0)

#define BAR_END()                                                              \
  __builtin_amdgcn_s_barrier();                                                \
  __builtin_amdgcn_sched_barrier(0)

template <int EPI>
__global__ __launch_bounds__(512, 2) void gemm256(const unsigned short* __restrict__ A,
                                                  const unsigned short* __restrict__ W,
                                                  const float* __restrict__ bias,
                                                  unsigned short* __restrict__ Cout,
                                                  int Ndim, int Kdim, int Ks) {
  __shared__ unsigned short As[2][16384];  // [buf][256r x 64k]
  __shared__ unsigned short Bs[2][16384];
  const int tid = threadIdx.x;
  const int wave = tid >> 6;
  const int lane = tid & 63;
  const int wm = wave >> 2;  // 0..1
  const int wn = wave & 3;   // 0..3

  // bijective XCD chunked swizzle (m204) over (x,y); bm-fastest in chunk so
  // each XCD's B (weight) slab stays L2-resident while A streams.
  const int gx = gridDim.x, gy = gridDim.y;
  const int nwg = gx * gy;
  const int lin = blockIdx.x + blockIdx.y * gx;
  const int q8 = nwg >> 3, r8 = nwg & 7;
  const int xcd = lin & 7, cidx = lin >> 3;
  const int cbase = (xcd < r8) ? xcd * (q8 + 1) : r8 * (q8 + 1) + (xcd - r8) * q8;
  const int swz = cbase + cidx;
  const int bm0 = (swz % gy) * 256;
  const int bn0 = (swz / gy) * 256;
  const int kz0 = blockIdx.z * Ks;

  // staging: half-tile = 128r x 64k = 16KB = 512thr x 16B x 2 instrs
  const int r0 = tid >> 3;         // 0..63
  const int c0 = (tid & 7) * 8;    // 0..56
  const size_t rowstep = (size_t)64 * Kdim;

#define STAGEH(MAT, rowg, buf, LDSARR, h, kt)                                  \
  do {                                                                         \
    const unsigned short* g = MAT + (size_t)((rowg) + (h) * 128 + r0) * Kdim + \
                              kz0 + (kt) * 64 + c0;                            \
    char* lb = (char*)&LDSARR[buf][0] + (h) * 16384 + wave * 1024;             \
    GLOAD16(g, lb);                                                            \
    GLOAD16(g + rowstep, lb + 8192);                                           \
  } while (0)

  const int fr = lane & 15;
  const int kc = (lane >> 4) * 8;
  bf16x8 A0[2][4], A1[2][4], Bv[2][2];
  f32x4 acc[2][2][4][2] = {};

#define RD_A(SET, buf, rh)                                                     \
  _Pragma("unroll") for (int ks = 0; ks < 2; ++ks)                             \
      _Pragma("unroll") for (int fi = 0; fi < 4; ++fi)                         \
      SET[ks][fi] = *reinterpret_cast<const bf16x8*>(                          \
          &As[buf][(wm * 128 + (rh) * 64 + fi * 16 + fr) * 64 + ks * 32 + kc]);

#define RD_B(buf, ch)                                                          \
  _Pragma("unroll") for (int ks = 0; ks < 2; ++ks)                             \
      _Pragma("unroll") for (int fj = 0; fj < 2; ++fj)                         \
      Bv[ks][fj] = *reinterpret_cast<const bf16x8*>(                           \
          &Bs[buf][(wn * 64 + (ch) * 32 + fj * 16 + fr) * 64 + ks * 32 + kc]);

#define MFMA_Q(rh, ch, ASET)                                                   \
  __builtin_amdgcn_s_setprio(1);                                               \
  _Pragma("unroll") for (int ks = 0; ks < 2; ++ks)                             \
      _Pragma("unroll") for (int fi = 0; fi < 4; ++fi)                         \
      _Pragma("unroll") for (int fj = 0; fj < 2; ++fj)                         \
      acc[rh][ch][fi][fj] = __builtin_amdgcn_mfma_f32_16x16x32_bf16(           \
          ASET[ks][fi], Bv[ks][fj], acc[rh][ch][fi][fj], 0, 0, 0);             \
  __builtin_amdgcn_s_setprio(0)

  const int nt = Ks >> 6;  // K-tiles; even, >= 2
  // prologue: tile0 (4 halves)->buf0, tile1 (Alo,Ahi,Blo)->buf1  [14 loads]
  STAGEH(A, bm0, 0, As, 0, 0);
  STAGEH(A, bm0, 0, As, 1, 0);
  STAGEH(W, bn0, 0, Bs, 0, 0);
  STAGEH(W, bn0, 0, Bs, 1, 0);
  STAGEH(A, bm0, 1, As, 0, 1);
  STAGEH(A, bm0, 1, As, 1, 1);
  STAGEH(W, bn0, 1, Bs, 0, 1);
  asm volatile("s_waitcnt vmcnt(6)" ::: "memory");  // tile0 fully landed
  BAR_END();

  const int npair = nt >> 1;
  for (int i = 0; i < npair; ++i) {
    const int t1 = 2 * i + 1, t2 = 2 * i + 2, t3 = 2 * i + 3;
    const bool pf = (t2 < nt);
    // ---- phases 0-3: compute tile 2i (buf0) ----
    RD_A(A0, 0, 0);
    RD_B(0, 0);
    STAGEH(W, bn0, 1, Bs, 1, t1);  // B-hi(t1)->buf1 (region idle since ph6 prev)
    BAR_MID();
    MFMA_Q(0, 0, A0);
    BAR_END();

    RD_A(A1, 0, 1);
    BAR_MID();
    MFMA_Q(1, 0, A1);
    BAR_END();

    RD_B(0, 1);
    if (pf) STAGEH(A, bm0, 0, As, 0, t2);  // A-lo read drained ph1
    BAR_MID();
    MFMA_Q(1, 1, A1);
    BAR_END();

    if (pf) {
      STAGEH(A, bm0, 0, As, 1, t2);
      STAGEH(W, bn0, 0, Bs, 0, t2);  // B-lo read drained ph2
    }
    BAR_MID();
    MFMA_Q(0, 1, A0);
    if (pf)
      asm volatile("s_waitcnt vmcnt(6)" ::: "memory");  // tile t1 landed
    else
      asm volatile("s_waitcnt vmcnt(0)" ::: "memory");
    BAR_END();

    // ---- phases 4-7: compute tile 2i+1 (buf1) ----
    RD_A(A0, 1, 0);
    RD_B(1, 0);
    if (pf) STAGEH(W, bn0, 0, Bs, 1, t2);  // B-hi(t2)->buf0
    BAR_MID();
    MFMA_Q(0, 0, A0);
    BAR_END();

    RD_A(A1, 1, 1);
    BAR_MID();
    MFMA_Q(1, 0, A1);
    BAR_END();

    RD_B(1, 1);
    if (pf) STAGEH(A, bm0, 1, As, 0, t3);
    BAR_MID();
    MFMA_Q(1, 1, A1);
    BAR_END();

    if (pf) {
      STAGEH(A, bm0, 1, As, 1, t3);
      STAGEH(W, bn0, 1, Bs, 0, t3);
    }
    BAR_MID();
    MFMA_Q(0, 1, A0);
    if (pf) asm volatile("s_waitcnt vmcnt(6)" ::: "memory");  // tile t2 landed
    BAR_END();
  }

#undef STAGEH
#undef RD_A
#undef RD_B
#undef MFMA_Q

  // epilogue: C/D layout col=lane&15, row=(lane>>4)*4+reg (m89/m91)
  const int rr = (lane >> 4) * 4;
  const int cc = lane & 15;
  const bool addb = (EPI != 2) || (blockIdx.z == 0);
  unsigned short* outZ =
      Cout + (EPI == 2 ? (size_t)blockIdx.z * ((size_t)gy * 256) * Ndim : 0);
#pragma unroll
  for (int rh = 0; rh < 2; ++rh)
#pragma unroll
    for (int ch = 0; ch < 2; ++ch)
#pragma unroll
      for (int fj = 0; fj < 2; ++fj) {
        const int n = bn0 + wn * 64 + ch * 32 + fj * 16 + cc;
        const float bv = addb ? bias[n] : 0.0f;
#pragma unroll
        for (int fi = 0; fi < 4; ++fi)
#pragma unroll
          for (int r = 0; r < 4; ++r) {
            const int m = bm0 + wm * 128 + rh * 64 + fi * 16 + rr + r;
            float v = acc[rh][ch][fi][fj][r] + bv;
            if (EPI == 1) v = 0.5f * v * (1.0f + erff(v * 0.70710678118654752f));
            outZ[(size_t)m * Ndim + n] = f2bf(v);
          }
      }
}

// ---------------- banded attention: one wave per (b,h,q), lane = d ----------
__global__ __launch_bounds__(256) void attn_band(const unsigned short* __restrict__ qkv,
                                                 unsigned short* __restrict__ outp) {
  const int gw = blockIdx.x * 4 + (threadIdx.x >> 6);
  const int lane = threadIdx.x & 63;
  const int q = gw & (SEQ - 1);
  const int bh = gw >> 10;
  const int h = bh & (NHEAD - 1);
  const int b = bh >> 4;
  const size_t row0 = (size_t)(b * SEQ + q);
  const size_t stride = 3 * DMODEL;
  const float qv = bf2f(qkv[row0 * stride + h * HDIM + lane]);

  float sc[KBAND];
  float mx = -1e30f;
#pragma unroll
  for (int jj = 0; jj < KBAND; ++jj) {
    const int j = q + jj;
    const int jc = (j < SEQ) ? j : (SEQ - 1);
    float kv = bf2f(qkv[(size_t)(b * SEQ + jc) * stride + DMODEL + h * HDIM + lane]);
    float p = qv * kv;
#pragma unroll
    for (int m = 32; m; m >>= 1) p += __shfl_xor(p, m);
    p *= 0.125f;
    p = (j < SEQ) ? p : -1e30f;
    sc[jj] = p;
    mx = fmaxf(mx, p);
  }
  float denom = 0.f;
  float ov = 0.f;
#pragma unroll
  for (int jj = 0; jj < KBAND; ++jj) {
    const int j = q + jj;
    const int jc = (j < SEQ) ? j : (SEQ - 1);
    float p = __expf(sc[jj] - mx);
    p = (j < SEQ) ? p : 0.f;
    denom += p;
    ov += p * bf2f(qkv[(size_t)(b * SEQ + jc) * stride + 2 * DMODEL + h * HDIM + lane]);
  }
  ov /= denom;
  outp[row0 * DMODEL + h * HDIM + lane] = f2bf(ov);
}

// ---------------- residual + 4-way bf16 split-K reduce + LayerNorm ----------
__global__ __launch_bounds__(256) void add_ln4(const float* __restrict__ resid,
                                               const unsigned short* __restrict__ part,
                                               const float* __restrict__ gw,
                                               const float* __restrict__ gb,
                                               float* __restrict__ xf,
                                               unsigned short* __restrict__ xb) {
  const int row = blockIdx.x;
  const int tid = threadIdx.x;
  const size_t slab = (size_t)MROWS * DMODEL;
  const float* rp = resid + (size_t)row * DMODEL;
  const unsigned short* pp = part + (size_t)row * DMODEL;
  float v[4];
  float s = 0.f, s2 = 0.f;
#pragma unroll
  for (int i = 0; i < 4; ++i) {
    const int idx = tid + i * 256;
    float a = rp[idx];
#pragma unroll
    for (int z = 0; z < 4; ++z) a += bf2f(pp[z * slab + idx]);
    v[i] = a;
    s += a;
    s2 += a * a;
  }
#pragma unroll
  for (int m = 32; m; m >>= 1) {
    s += __shfl_xor(s, m);
    s2 += __shfl_xor(s2, m);
  }
  __shared__ float wsm[8];
  const int wave = tid >> 6, lane = tid & 63;
  if (lane == 0) {
    wsm[wave] = s;
    wsm[4 + wave] = s2;
  }
  __syncthreads();
  s = wsm[0] + wsm[1] + wsm[2] + wsm[3];
  s2 = wsm[4] + wsm[5] + wsm[6] + wsm[7];
  const float mean = s * (1.f / DMODEL);
  const float var = s2 * (1.f / DMODEL) - mean * mean;
  const float rstd = rsqrtf(var + 1e-5f);
#pragma unroll
  for (int i = 0; i < 4; ++i) {
    const int idx = tid + i * 256;
    const float y = (v[i] - mean) * rstd * gw[idx] + gb[idx];
    xf[(size_t)row * DMODEL + idx] = y;
    xb[(size_t)row * DMODEL + idx] = f2bf(y);
  }
}

extern "C" void kernel_launch(void* const* d_in, const int* in_sizes, int n_in,
                              void* d_out, int out_size, void* d_ws, size_t ws_size,
                              hipStream_t stream) {
  const float* src  = (const float*)d_in[0];
  const float* Wqkv = (const float*)d_in[1];
  const float* bqkv = (const float*)d_in[2];
  const float* Wo   = (const float*)d_in[3];
  const float* bo   = (const float*)d_in[4];
  const float* W1   = (const float*)d_in[5];
  const float* b1   = (const float*)d_in[6];
  const float* W2   = (const float*)d_in[7];
  const float* b2   = (const float*)d_in[8];
  const float* ln1w = (const float*)d_in[9];
  const float* ln1b = (const float*)d_in[10];
  const float* ln2w = (const float*)d_in[11];
  const float* ln2b = (const float*)d_in[12];
  float* out = (float*)d_out;

  // workspace carve-up (~193 MB of 209.7 MB)
  char* p = (char*)d_ws;
  unsigned short* wqkv_b = (unsigned short*)p; p += (size_t)LNUM * 3072 * 1024 * 2;
  unsigned short* wo_b   = (unsigned short*)p; p += (size_t)LNUM * 1024 * 1024 * 2;
  unsigned short* w1_b   = (unsigned short*)p; p += (size_t)LNUM * 4096 * 1024 * 2;
  unsigned short* w2_b   = (unsigned short*)p; p += (size_t)LNUM * 1024 * 4096 * 2;
  float*          xf     = (float*)p;          p += (size_t)MROWS * DMODEL * 4;
  unsigned short* xb     = (unsigned short*)p; p += (size_t)MROWS * DMODEL * 2;
  // region R: [qkvb 24MB | aob 8MB] aliased by [hb 32MB], then part 4x8MB bf16
  char* R = p;
  unsigned short* qkvb = (unsigned short*)R;
  unsigned short* aob  = (unsigned short*)(R + (size_t)MROWS * 3 * DMODEL * 2);
  unsigned short* hb   = (unsigned short*)R;
  unsigned short* part = (unsigned short*)(R + (size_t)MROWS * 4096 * 2);
  p = R + (size_t)MROWS * 4096 * 2 + (size_t)4 * MROWS * DMODEL * 2;
  if (ws_size < (size_t)(p - (char*)d_ws)) return;

  cvt_bf16<<<(long)LNUM * 3072 * 1024 / 1024, 256, 0, stream>>>(Wqkv, wqkv_b, (long)LNUM * 3072 * 1024);
  cvt_bf16<<<(long)LNUM * 1024 * 1024 / 1024, 256, 0, stream>>>(Wo, wo_b, (long)LNUM * 1024 * 1024);
  cvt_bf16<<<(long)LNUM * 4096 * 1024 / 1024, 256, 0, stream>>>(W1, w1_b, (long)LNUM * 4096 * 1024);
  cvt_bf16<<<(long)LNUM * 1024 * 4096 / 1024, 256, 0, stream>>>(W2, w2_b, (long)LNUM * 1024 * 4096);
  cvt_bf16<<<(long)MROWS * DMODEL / 1024, 256, 0, stream>>>(src, xb, (long)MROWS * DMODEL);

  for (int l = 0; l < LNUM; ++l) {
    // QKV: [4096,1024] x [3072,1024]^T -> bf16 [4096,3072]
    gemm256<0><<<dim3(3072 / 256, MROWS / 256, 1), 512, 0, stream>>>(
        xb, wqkv_b + (size_t)l * 3072 * 1024, bqkv + l * 3072, qkvb, 3072, 1024, 1024);
    attn_band<<<(BATCH * NHEAD * SEQ) / 4, 256, 0, stream>>>(qkvb, aob);
    // Wo: split-K=4 (Ks=256) -> bf16 partial slabs
    gemm256<2><<<dim3(1024 / 256, MROWS / 256, 4), 512, 0, stream>>>(
        aob, wo_b + (size_t)l * 1024 * 1024, bo + l * 1024, part, 1024, 1024, 256);
    add_ln4<<<MROWS, 256, 0, stream>>>(l == 0 ? src : xf, part,
                                       ln1w + l * DMODEL, ln1b + l * DMODEL, xf, xb);
    // W1 + gelu: [4096,1024] x [4096,1024]^T -> bf16 [4096,4096]
    gemm256<1><<<dim3(FDIM / 256, MROWS / 256, 1), 512, 0, stream>>>(
        xb, w1_b + (size_t)l * 4096 * 1024, b1 + l * FDIM, hb, FDIM, 1024, 1024);
    // W2: split-K=4 (Ks=1024) -> bf16 partial slabs
    gemm256<2><<<dim3(1024 / 256, MROWS / 256, 4), 512, 0, stream>>>(
        hb, w2_b + (size_t)l * 1024 * 4096, b2 + l * 1024, part, 1024, 4096, 1024);
    float* dst = (l == LNUM - 1) ? out : xf;
    add_ln4<<<MROWS, 256, 0, stream>>>(xf, part,
                                       ln2w + l * DMODEL, ln2b + l * DMODEL, dst, xb);
  }
}

// Round 5
// 984.815 us; speedup vs baseline: 1.2443x; 1.1278x over previous
//
#include <hip/hip_runtime.h>

#define LNUM 4
#define DMODEL 1024
#define NHEAD 16
#define FDIM 4096
#define BATCH 4
#define SEQ 1024
#define HDIM 64
#define KBAND 8
#define MROWS (BATCH * SEQ)

typedef __attribute__((ext_vector_type(8))) __bf16 bf16x8;
typedef __attribute__((ext_vector_type(4))) float f32x4;

__device__ __forceinline__ unsigned short f2bf(float f) {
  unsigned int u = __builtin_bit_cast(unsigned int, f);
  u = u + 0x7fffu + ((u >> 16) & 1u);
  return (unsigned short)(u >> 16);
}
__device__ __forceinline__ float bf2f(unsigned short h) {
  unsigned int u = ((unsigned int)h) << 16;
  return __builtin_bit_cast(float, u);
}

#define GLOAD16(gp, lp)                                                        \
  __builtin_amdgcn_global_load_lds(                                            \
      (const __attribute__((address_space(1))) void*)(gp),                     \
      (__attribute__((address_space(3))) void*)(lp), 16, 0, 0)

// ---------------- fp32 -> bf16 conversion -----------------------------------
__global__ __launch_bounds__(256) void cvt_bf16(const float* __restrict__ in,
                                                unsigned short* __restrict__ out,
                                                long n) {
  long i = ((long)blockIdx.x * 256 + threadIdx.x) * 4;
  if (i + 3 < n) {
    float4 v = *reinterpret_cast<const float4*>(in + i);
    ushort4 o;
    o.x = f2bf(v.x);
    o.y = f2bf(v.y);
    o.z = f2bf(v.z);
    o.w = f2bf(v.w);
    *reinterpret_cast<ushort4*>(out + i) = o;
  }
}

// ---------------- 256x256 8-phase bf16 GEMM, C = A * W^T + bias -------------
// A: [M,K] bf16 rm. W: [N,K] bf16 rm. 512 thr = 8 waves (2m x 4n).
// BK=64, LDS 128KB double-buffer, per-wave out 128x64 (acc 2x2x4x2 f32x4).
// T2 LDS swizzle: logical (row,col) stored at row*64 + (col ^ ((row&7)<<3)).
//   write side: linear LDS dest + pre-swizzled GLOBAL source column (m173);
//   read side: same XOR on the ds_read index. Bank-quad = (lane>>4)^(lane&7)
//   -> 8 lanes/quad = conflict-free minimum.
// Counted vmcnt(6) at phases 3/7 only (T4); setprio around MFMA (T5).
// blockIdx.z = K-split (range [z*Ks,(z+1)*Ks)).
// EPI: 0 = bf16 (+bias), 1 = bf16 (+bias, exact gelu),
//      2 = bf16 PARTIAL slab per z (bias only z==0).
#define BAR_MID()                                                              \
  __builtin_amdgcn_s_barrier();                                                \
  asm volatile("s_waitcnt lgkmcnt(0)" ::: "memory");                           \
  __builtin_amdgcn_sched_barrier(0)

#define BAR_END()                                                              \
  __builtin_amdgcn_s_barrier();                                                \
  __builtin_amdgcn_sched_barrier(0)

template <int EPI>
__global__ __launch_bounds__(512, 2) void gemm256(const unsigned short* __restrict__ A,
                                                  const unsigned short* __restrict__ W,
                                                  const float* __restrict__ bias,
                                                  unsigned short* __restrict__ Cout,
                                                  int Ndim, int Kdim, int Ks) {
  __shared__ unsigned short As[2][16384];  // [buf][256r x 64k, col-swizzled]
  __shared__ unsigned short Bs[2][16384];
  const int tid = threadIdx.x;
  const int wave = tid >> 6;
  const int lane = tid & 63;
  const int wm = wave >> 2;  // 0..1
  const int wn = wave & 3;   // 0..3

  // bijective XCD chunked swizzle (m204) over (x,y); bm-fastest in chunk so
  // each XCD's B (weight) slab stays L2-resident while A streams.
  const int gx = gridDim.x, gy = gridDim.y;
  const int nwg = gx * gy;
  const int lin = blockIdx.x + blockIdx.y * gx;
  const int q8 = nwg >> 3, r8 = nwg & 7;
  const int xcd = lin & 7, cidx = lin >> 3;
  const int cbase = (xcd < r8) ? xcd * (q8 + 1) : r8 * (q8 + 1) + (xcd - r8) * q8;
  const int swz = cbase + cidx;
  const int bm0 = (swz % gy) * 256;
  const int bn0 = (swz / gy) * 256;
  const int kz0 = blockIdx.z * Ks;

  // staging: half-tile = 128r x 64k = 16KB = 512thr x 16B x 2 instrs
  // T2 pre-swizzled source column: LDS row&7 == (tid>>3)&7 for every STAGEH
  // (all other row terms are multiples of 8), so fetch col = lin_col ^ row&7.
  const int r0 = tid >> 3;                                  // 0..63
  const int c0 = (((tid & 7) ^ ((tid >> 3) & 7)) << 3);     // swizzled 0..56
  const size_t rowstep = (size_t)64 * Kdim;

#define STAGEH(MAT, rowg, buf, LDSARR, h, kt)                                  \
  do {                                                                         \
    const unsigned short* g = MAT + (size_t)((rowg) + (h) * 128 + r0) * Kdim + \
                              kz0 + (kt) * 64 + c0;                            \
    char* lb = (char*)&LDSARR[buf][0] + (h) * 16384 + wave * 1024;             \
    GLOAD16(g, lb);                                                            \
    GLOAD16(g + rowstep, lb + 8192);                                           \
  } while (0)

  const int fr = lane & 15;
  const int kc = (lane >> 4) * 8;
  const int fsw = (fr & 7) << 3;  // read-side XOR (row&7 == fr&7)
  bf16x8 A0[2][4], A1[2][4], Bv[2][2];
  f32x4 acc[2][2][4][2] = {};

#define RD_A(SET, buf, rh)                                                     \
  _Pragma("unroll") for (int ks = 0; ks < 2; ++ks)                             \
      _Pragma("unroll") for (int fi = 0; fi < 4; ++fi)                         \
      SET[ks][fi] = *reinterpret_cast<const bf16x8*>(                          \
          &As[buf][(wm * 128 + (rh) * 64 + fi * 16 + fr) * 64 +                \
                   ((ks * 32 + kc) ^ fsw)]);

#define RD_B(buf, ch)                                                          \
  _Pragma("unroll") for (int ks = 0; ks < 2; ++ks)                             \
      _Pragma("unroll") for (int fj = 0; fj < 2; ++fj)                         \
      Bv[ks][fj] = *reinterpret_cast<const bf16x8*>(                           \
          &Bs[buf][(wn * 64 + (ch) * 32 + fj * 16 + fr) * 64 +                 \
                   ((ks * 32 + kc) ^ fsw)]);

#define MFMA_Q(rh, ch, ASET)                                                   \
  __builtin_amdgcn_s_setprio(1);                                               \
  _Pragma("unroll") for (int ks = 0; ks < 2; ++ks)                             \
      _Pragma("unroll") for (int fi = 0; fi < 4; ++fi)                         \
      _Pragma("unroll") for (int fj = 0; fj < 2; ++fj)                         \
      acc[rh][ch][fi][fj] = __builtin_amdgcn_mfma_f32_16x16x32_bf16(           \
          ASET[ks][fi], Bv[ks][fj], acc[rh][ch][fi][fj], 0, 0, 0);             \
  __builtin_amdgcn_s_setprio(0)

  const int nt = Ks >> 6;  // K-tiles; even, >= 2
  // prologue: tile0 (4 halves)->buf0, tile1 (Alo,Ahi,Blo)->buf1  [14 loads]
  STAGEH(A, bm0, 0, As, 0, 0);
  STAGEH(A, bm0, 0, As, 1, 0);
  STAGEH(W, bn0, 0, Bs, 0, 0);
  STAGEH(W, bn0, 0, Bs, 1, 0);
  STAGEH(A, bm0, 1, As, 0, 1);
  STAGEH(A, bm0, 1, As, 1, 1);
  STAGEH(W, bn0, 1, Bs, 0, 1);
  asm volatile("s_waitcnt vmcnt(6)" ::: "memory");  // tile0 fully landed
  BAR_END();

  const int npair = nt >> 1;
  for (int i = 0; i < npair; ++i) {
    const int t1 = 2 * i + 1, t2 = 2 * i + 2, t3 = 2 * i + 3;
    const bool pf = (t2 < nt);
    // ---- phases 0-3: compute tile 2i (buf0) ----
    RD_A(A0, 0, 0);
    RD_B(0, 0);
    STAGEH(W, bn0, 1, Bs, 1, t1);  // B-hi(t1)->buf1 (region idle since ph6 prev)
    BAR_MID();
    MFMA_Q(0, 0, A0);
    BAR_END();

    RD_A(A1, 0, 1);
    BAR_MID();
    MFMA_Q(1, 0, A1);
    BAR_END();

    RD_B(0, 1);
    if (pf) STAGEH(A, bm0, 0, As, 0, t2);  // A-lo read drained ph1
    BAR_MID();
    MFMA_Q(1, 1, A1);
    BAR_END();

    if (pf) {
      STAGEH(A, bm0, 0, As, 1, t2);
      STAGEH(W, bn0, 0, Bs, 0, t2);  // B-lo read drained ph2
    }
    BAR_MID();
    MFMA_Q(0, 1, A0);
    if (pf)
      asm volatile("s_waitcnt vmcnt(6)" ::: "memory");  // tile t1 landed
    else
      asm volatile("s_waitcnt vmcnt(0)" ::: "memory");
    BAR_END();

    // ---- phases 4-7: compute tile 2i+1 (buf1) ----
    RD_A(A0, 1, 0);
    RD_B(1, 0);
    if (pf) STAGEH(W, bn0, 0, Bs, 1, t2);  // B-hi(t2)->buf0
    BAR_MID();
    MFMA_Q(0, 0, A0);
    BAR_END();

    RD_A(A1, 1, 1);
    BAR_MID();
    MFMA_Q(1, 0, A1);
    BAR_END();

    RD_B(1, 1);
    if (pf) STAGEH(A, bm0, 1, As, 0, t3);
    BAR_MID();
    MFMA_Q(1, 1, A1);
    BAR_END();

    if (pf) {
      STAGEH(A, bm0, 1, As, 1, t3);
      STAGEH(W, bn0, 1, Bs, 0, t3);
    }
    BAR_MID();
    MFMA_Q(0, 1, A0);
    if (pf) asm volatile("s_waitcnt vmcnt(6)" ::: "memory");  // tile t2 landed
    BAR_END();
  }

#undef STAGEH
#undef RD_A
#undef RD_B
#undef MFMA_Q

  // epilogue: C/D layout col=lane&15, row=(lane>>4)*4+reg (m89/m91)
  const int rr = (lane >> 4) * 4;
  const int cc = lane & 15;
  const bool addb = (EPI != 2) || (blockIdx.z == 0);
  unsigned short* outZ =
      Cout + (EPI == 2 ? (size_t)blockIdx.z * ((size_t)gy * 256) * Ndim : 0);
#pragma unroll
  for (int rh = 0; rh < 2; ++rh)
#pragma unroll
    for (int ch = 0; ch < 2; ++ch)
#pragma unroll
      for (int fj = 0; fj < 2; ++fj) {
        const int n = bn0 + wn * 64 + ch * 32 + fj * 16 + cc;
        const float bv = addb ? bias[n] : 0.0f;
#pragma unroll
        for (int fi = 0; fi < 4; ++fi)
#pragma unroll
          for (int r = 0; r < 4; ++r) {
            const int m = bm0 + wm * 128 + rh * 64 + fi * 16 + rr + r;
            float v = acc[rh][ch][fi][fj][r] + bv;
            if (EPI == 1) v = 0.5f * v * (1.0f + erff(v * 0.70710678118654752f));
            outZ[(size_t)m * Ndim + n] = f2bf(v);
          }
      }
}

// ---------------- banded attention: one wave per (b,h,q), lane = d ----------
__global__ __launch_bounds__(256) void attn_band(const unsigned short* __restrict__ qkv,
                                                 unsigned short* __restrict__ outp) {
  const int gw = blockIdx.x * 4 + (threadIdx.x >> 6);
  const int lane = threadIdx.x & 63;
  const int q = gw & (SEQ - 1);
  const int bh = gw >> 10;
  const int h = bh & (NHEAD - 1);
  const int b = bh >> 4;
  const size_t row0 = (size_t)(b * SEQ + q);
  const size_t stride = 3 * DMODEL;
  const float qv = bf2f(qkv[row0 * stride + h * HDIM + lane]);

  float sc[KBAND];
  float mx = -1e30f;
#pragma unroll
  for (int jj = 0; jj < KBAND; ++jj) {
    const int j = q + jj;
    const int jc = (j < SEQ) ? j : (SEQ - 1);
    float kv = bf2f(qkv[(size_t)(b * SEQ + jc) * stride + DMODEL + h * HDIM + lane]);
    float p = qv * kv;
#pragma unroll
    for (int m = 32; m; m >>= 1) p += __shfl_xor(p, m);
    p *= 0.125f;
    p = (j < SEQ) ? p : -1e30f;
    sc[jj] = p;
    mx = fmaxf(mx, p);
  }
  float denom = 0.f;
  float ov = 0.f;
#pragma unroll
  for (int jj = 0; jj < KBAND; ++jj) {
    const int j = q + jj;
    const int jc = (j < SEQ) ? j : (SEQ - 1);
    float p = __expf(sc[jj] - mx);
    p = (j < SEQ) ? p : 0.f;
    denom += p;
    ov += p * bf2f(qkv[(size_t)(b * SEQ + jc) * stride + 2 * DMODEL + h * HDIM + lane]);
  }
  ov /= denom;
  outp[row0 * DMODEL + h * HDIM + lane] = f2bf(ov);
}

// ---------------- residual + 4-way bf16 split-K reduce + LayerNorm ----------
__global__ __launch_bounds__(256) void add_ln4(const float* __restrict__ resid,
                                               const unsigned short* __restrict__ part,
                                               const float* __restrict__ gw,
                                               const float* __restrict__ gb,
                                               float* __restrict__ xf,
                                               unsigned short* __restrict__ xb) {
  const int row = blockIdx.x;
  const int tid = threadIdx.x;
  const size_t slab = (size_t)MROWS * DMODEL;
  const float* rp = resid + (size_t)row * DMODEL;
  const unsigned short* pp = part + (size_t)row * DMODEL;
  float v[4];
  float s = 0.f, s2 = 0.f;
#pragma unroll
  for (int i = 0; i < 4; ++i) {
    const int idx = tid + i * 256;
    float a = rp[idx];
#pragma unroll
    for (int z = 0; z < 4; ++z) a += bf2f(pp[z * slab + idx]);
    v[i] = a;
    s += a;
    s2 += a * a;
  }
#pragma unroll
  for (int m = 32; m; m >>= 1) {
    s += __shfl_xor(s, m);
    s2 += __shfl_xor(s2, m);
  }
  __shared__ float wsm[8];
  const int wave = tid >> 6, lane = tid & 63;
  if (lane == 0) {
    wsm[wave] = s;
    wsm[4 + wave] = s2;
  }
  __syncthreads();
  s = wsm[0] + wsm[1] + wsm[2] + wsm[3];
  s2 = wsm[4] + wsm[5] + wsm[6] + wsm[7];
  const float mean = s * (1.f / DMODEL);
  const float var = s2 * (1.f / DMODEL) - mean * mean;
  const float rstd = rsqrtf(var + 1e-5f);
#pragma unroll
  for (int i = 0; i < 4; ++i) {
    const int idx = tid + i * 256;
    const float y = (v[i] - mean) * rstd * gw[idx] + gb[idx];
    xf[(size_t)row * DMODEL + idx] = y;
    xb[(size_t)row * DMODEL + idx] = f2bf(y);
  }
}

extern "C" void kernel_launch(void* const* d_in, const int* in_sizes, int n_in,
                              void* d_out, int out_size, void* d_ws, size_t ws_size,
                              hipStream_t stream) {
  const float* src  = (const float*)d_in[0];
  const float* Wqkv = (const float*)d_in[1];
  const float* bqkv = (const float*)d_in[2];
  const float* Wo   = (const float*)d_in[3];
  const float* bo   = (const float*)d_in[4];
  const float* W1   = (const float*)d_in[5];
  const float* b1   = (const float*)d_in[6];
  const float* W2   = (const float*)d_in[7];
  const float* b2   = (const float*)d_in[8];
  const float* ln1w = (const float*)d_in[9];
  const float* ln1b = (const float*)d_in[10];
  const float* ln2w = (const float*)d_in[11];
  const float* ln2b = (const float*)d_in[12];
  float* out = (float*)d_out;

  // workspace carve-up (~193 MB of 209.7 MB)
  char* p = (char*)d_ws;
  unsigned short* wqkv_b = (unsigned short*)p; p += (size_t)LNUM * 3072 * 1024 * 2;
  unsigned short* wo_b   = (unsigned short*)p; p += (size_t)LNUM * 1024 * 1024 * 2;
  unsigned short* w1_b   = (unsigned short*)p; p += (size_t)LNUM * 4096 * 1024 * 2;
  unsigned short* w2_b   = (unsigned short*)p; p += (size_t)LNUM * 1024 * 4096 * 2;
  float*          xf     = (float*)p;          p += (size_t)MROWS * DMODEL * 4;
  unsigned short* xb     = (unsigned short*)p; p += (size_t)MROWS * DMODEL * 2;
  // region R: [qkvb 24MB | aob 8MB] aliased by [hb 32MB], then part 4x8MB bf16
  char* R = p;
  unsigned short* qkvb = (unsigned short*)R;
  unsigned short* aob  = (unsigned short*)(R + (size_t)MROWS * 3 * DMODEL * 2);
  unsigned short* hb   = (unsigned short*)R;
  unsigned short* part = (unsigned short*)(R + (size_t)MROWS * 4096 * 2);
  p = R + (size_t)MROWS * 4096 * 2 + (size_t)4 * MROWS * DMODEL * 2;
  if (ws_size < (size_t)(p - (char*)d_ws)) return;

  cvt_bf16<<<(long)LNUM * 3072 * 1024 / 1024, 256, 0, stream>>>(Wqkv, wqkv_b, (long)LNUM * 3072 * 1024);
  cvt_bf16<<<(long)LNUM * 1024 * 1024 / 1024, 256, 0, stream>>>(Wo, wo_b, (long)LNUM * 1024 * 1024);
  cvt_bf16<<<(long)LNUM * 4096 * 1024 / 1024, 256, 0, stream>>>(W1, w1_b, (long)LNUM * 4096 * 1024);
  cvt_bf16<<<(long)LNUM * 1024 * 4096 / 1024, 256, 0, stream>>>(W2, w2_b, (long)LNUM * 1024 * 4096);
  cvt_bf16<<<(long)MROWS * DMODEL / 1024, 256, 0, stream>>>(src, xb, (long)MROWS * DMODEL);

  for (int l = 0; l < LNUM; ++l) {
    // QKV: [4096,1024] x [3072,1024]^T -> bf16 [4096,3072]
    gemm256<0><<<dim3(3072 / 256, MROWS / 256, 1), 512, 0, stream>>>(
        xb, wqkv_b + (size_t)l * 3072 * 1024, bqkv + l * 3072, qkvb, 3072, 1024, 1024);
    attn_band<<<(BATCH * NHEAD * SEQ) / 4, 256, 0, stream>>>(qkvb, aob);
    // Wo: split-K=4 (Ks=256) -> bf16 partial slabs
    gemm256<2><<<dim3(1024 / 256, MROWS / 256, 4), 512, 0, stream>>>(
        aob, wo_b + (size_t)l * 1024 * 1024, bo + l * 1024, part, 1024, 1024, 256);
    add_ln4<<<MROWS, 256, 0, stream>>>(l == 0 ? src : xf, part,
                                       ln1w + l * DMODEL, ln1b + l * DMODEL, xf, xb);
    // W1 + gelu: [4096,1024] x [4096,1024]^T -> bf16 [4096,4096]
    gemm256<1><<<dim3(FDIM / 256, MROWS / 256, 1), 512, 0, stream>>>(
        xb, w1_b + (size_t)l * 4096 * 1024, b1 + l * FDIM, hb, FDIM, 1024, 1024);
    // W2: split-K=4 (Ks=1024) -> bf16 partial slabs
    gemm256<2><<<dim3(1024 / 256, MROWS / 256, 4), 512, 0, stream>>>(
        hb, w2_b + (size_t)l * 1024 * 4096, b2 + l * 1024, part, 1024, 4096, 1024);
    float* dst = (l == LNUM - 1) ? out : xf;
    add_ln4<<<MROWS, 256, 0, stream>>>(xf, part,
                                       ln2w + l * DMODEL, ln2b + l * DMODEL, dst, xb);
  }
}